// Round 1
// baseline (226.013 us; speedup 1.0000x reference)
//
#include <hip/hip_runtime.h>

// ConvCapsuleLayer: B=2, H=W=48, IN_CAPS=8, ATOMS=16, KER=3, STRIDE=1,
// OUT_CAPS=16, ROUTINGS=3.  Ho=Wo=46, N = 2*46*46 = 4232 output pixels.
//
// One block of 256 threads per output pixel. Thread t = (o = t>>4, e = t&15),
// e = a*4+c indexes the 4x4 vote matrix. Each thread holds vote[k] for all
// k in [0,72) in registers, so the routing sum over k is thread-local.

#define IN_CAPS 8
#define OUT_CAPS 16
#define KK 9
#define KKIN 72          // 9*8
#define BATCH 2
#define H_IN 48
#define W_IN 48
#define HO 46
#define WO 46
#define CIN 136          // 8*17
#define NPIX (BATCH*HO*WO)   // 4232

__global__ __launch_bounds__(256, 2)
void capsule_routing_kernel(const float* __restrict__ x,
                            const float* __restrict__ Wg,
                            float* __restrict__ out)
{
    // padded LDS rows: 17/20 are coprime-ish with 32 banks -> conflict-free row access
    __shared__ alignas(16) float pose_s[KKIN][20];  // pose_s[k][atom], float4-readable
    __shared__ float act_s[KKIN];
    __shared__ float logits_s[KKIN][17];
    __shared__ float coup_s[KKIN][17];
    __shared__ float w_s[IN_CAPS*OUT_CAPS*16];      // 2048 floats = 8KB

    const int tid = threadIdx.x;
    const int o = tid >> 4;        // out capsule
    const int e = tid & 15;        // atom index in 4x4 output
    const int a = e >> 2;          // row of 4x4
    const int c = e & 3;           // col of 4x4

    const int n   = blockIdx.x;
    const int b   = n / (HO*WO);
    const int rem = n - b*(HO*WO);
    const int ho  = rem / WO;
    const int wo  = rem - ho*WO;

    // ---- stage W into LDS (coalesced) ----
    for (int i = tid; i < IN_CAPS*OUT_CAPS*16; i += 256) w_s[i] = Wg[i];

    // ---- load 3x3 patch: 9 pixels x 136 ch; contiguous global runs of 408 floats ----
    for (int idx = tid; idx < KK*CIN; idx += 256) {
        int p  = idx / CIN;
        int cc = idx - p*CIN;
        int py = p / 3, px = p - py*3;
        float val = x[(((b*H_IN + ho + py)*W_IN) + (wo + px))*CIN + cc];
        int ic = cc / 17;
        int aa = cc - ic*17;
        int k  = p*IN_CAPS + ic;
        if (aa == 16) act_s[k] = val;
        else          pose_s[k][aa] = val;
    }
    // ---- zero logits ----
    for (int idx = tid; idx < KKIN*16; idx += 256)
        logits_s[idx >> 4][idx & 15] = 0.f;

    __syncthreads();

    // ---- W fragment to registers: wreg[i][bb] = W[i][o][bb][c] ----
    float wreg[IN_CAPS][4];
    #pragma unroll
    for (int i = 0; i < IN_CAPS; ++i)
        #pragma unroll
        for (int bb = 0; bb < 4; ++bb)
            wreg[i][bb] = w_s[((i*OUT_CAPS + o)*4 + bb)*4 + c];

    // ---- votes: vote[k] = sum_b pose[k][a][b] * W[ic][o][b][c] ----
    float vote[KKIN];
    #pragma unroll
    for (int k = 0; k < KKIN; ++k) {
        const float4 pv = *reinterpret_cast<const float4*>(&pose_s[k][a*4]);
        const int ic = k & 7;
        vote[k] = pv.x*wreg[ic][0] + pv.y*wreg[ic][1]
                + pv.z*wreg[ic][2] + pv.w*wreg[ic][3];
    }

    // ---- routing-by-agreement, 3 iterations ----
    float v = 0.f;
    for (int r = 0; r < 3; ++r) {
        __syncthreads();   // logits writes (phase D) -> visible; coup_s free to rewrite
        // phase A: coup[k][o] = softmax_o(logits[k]) * act[k]   (72 row-threads)
        for (int k = tid; k < KKIN; k += 256) {
            float lg[16];
            float mx = -1e30f;
            #pragma unroll
            for (int j = 0; j < 16; ++j) { lg[j] = logits_s[k][j]; mx = fmaxf(mx, lg[j]); }
            float sum = 0.f;
            #pragma unroll
            for (int j = 0; j < 16; ++j) { lg[j] = __expf(lg[j] - mx); sum += lg[j]; }
            const float scale = act_s[k] / sum;
            #pragma unroll
            for (int j = 0; j < 16; ++j) coup_s[k][j] = lg[j] * scale;
        }
        __syncthreads();
        // phase B: s(o,e) = sum_k coup[k][o] * vote[k]   (thread-local over k)
        float s = 0.f;
        #pragma unroll
        for (int k = 0; k < KKIN; ++k)
            s = fmaf(coup_s[k][o], vote[k], s);
        // phase C: squash.  ||s||^2 over the 16 e-lanes (contiguous) via butterflies
        float sq = s*s;
        sq += __shfl_xor(sq, 1, 64);
        sq += __shfl_xor(sq, 2, 64);
        sq += __shfl_xor(sq, 4, 64);
        sq += __shfl_xor(sq, 8, 64);
        v = s * (sq / ((1.f + sq) * sqrtf(sq + 1e-7f)));
        // phase D: logits[k][o] += sum_e vote[k][o][e]*v[o][e]
        if (r < 2) {
            #pragma unroll
            for (int k = 0; k < KKIN; ++k) {
                float p = vote[k] * v;
                p += __shfl_xor(p, 1, 64);
                p += __shfl_xor(p, 2, 64);
                p += __shfl_xor(p, 4, 64);
                p += __shfl_xor(p, 8, 64);
                if (e == 0) logits_s[k][o] += p;
            }
        }
    }

    // ---- output: out[n][o][e], coalesced ----
    out[n*256 + tid] = v;
}

extern "C" void kernel_launch(void* const* d_in, const int* in_sizes, int n_in,
                              void* d_out, int out_size, void* d_ws, size_t ws_size,
                              hipStream_t stream) {
    const float* x  = (const float*)d_in[0];   // [2,48,48,136] fp32
    const float* Wt = (const float*)d_in[1];   // [8,16,4,4]    fp32
    float* out = (float*)d_out;                // [2,46,46,16,16] fp32
    capsule_routing_kernel<<<dim3(NPIX), dim3(256), 0, stream>>>(x, Wt, out);
}

// Round 2
// 223.208 us; speedup vs baseline: 1.0126x; 1.0126x over previous
//
#include <hip/hip_runtime.h>

// ConvCapsuleLayer: B=2, 48x48, IN_CAPS=8, ATOMS=16, KER=3, OUT_CAPS=16, R=3.
// One 256-thread block per output pixel n (N=4232). Thread t=(o=t>>4, e=t&15).
// vote[k] for all 72 k held in REGISTERS (launch_bounds(256,1) + pose/logits
// LDS aliasing makes rematerialization from LDS illegal after r=0 phase D).
// All 16-lane reductions via DPP adds (no ds_swizzle, no lgkmcnt stalls).

#define IN_CAPS 8
#define OUT_CAPS 16
#define KK 9
#define KKIN 72          // 9*8
#define BATCH 2
#define H_IN 48
#define W_IN 48
#define HO 46
#define WO 46
#define CIN 136          // 8*17
#define NPIX (BATCH*HO*WO)   // 4232

template<int CTRL>
__device__ __forceinline__ float dpp_f(float x) {
    return __int_as_float(
        __builtin_amdgcn_update_dpp(0, __float_as_int(x), CTRL, 0xF, 0xF, true));
}
// sum over the 16 lanes of a DPP row (our e-group): pure VALU, 4 adds
__device__ __forceinline__ float row_sum16(float x) {
    x += dpp_f<0xB1>(x);    // quad_perm [1,0,3,2]  (xor 1)
    x += dpp_f<0x4E>(x);    // quad_perm [2,3,0,1]  (xor 2)
    x += dpp_f<0x124>(x);   // row_ror:4 (quad sums replicated -> rotate+add ok)
    x += dpp_f<0x128>(x);   // row_ror:8
    return x;
}

__global__ __launch_bounds__(256, 1)
void capsule_routing_kernel(const float* __restrict__ x,
                            const float* __restrict__ Wg,
                            float* __restrict__ out)
{
    // pose rows (stride 20, float4-aligned) ALIASED with logits (stride 17):
    // writing logits in phase D kills pose -> votes must stay in registers.
    __shared__ alignas(16) float pose_or_logits[KKIN * 20];   // 5760 B
    __shared__ float act_s[KKIN];
    __shared__ float coup_t[OUT_CAPS][76];                    // [o][k] padded
    __shared__ float w_s[IN_CAPS * OUT_CAPS * 16];            // 8 KB

#define POSE(k, aa) pose_or_logits[(k) * 20 + (aa)]
#define LOGIT(k, j) pose_or_logits[(k) * 17 + (j)]

    const int tid = threadIdx.x;
    const int o = tid >> 4;        // out capsule
    const int e = tid & 15;        // atom = a*4+c
    const int a = e >> 2;
    const int c = e & 3;

    const int n   = blockIdx.x;
    const int b   = n / (HO * WO);
    const int rem = n - b * (HO * WO);
    const int ho  = rem / WO;
    const int wo  = rem - ho * WO;

    // ---- stage W (coalesced) ----
    for (int i = tid; i < IN_CAPS * OUT_CAPS * 16; i += 256) w_s[i] = Wg[i];

    // ---- 3x3 patch: 9 px x 136 ch ----
    for (int idx = tid; idx < KK * CIN; idx += 256) {
        int p  = idx / CIN;
        int cc = idx - p * CIN;
        int py = p / 3, px = p - py * 3;
        float val = x[(((b * H_IN + ho + py) * W_IN) + (wo + px)) * CIN + cc];
        int ic = cc / 17;
        int aa = cc - ic * 17;
        int k  = p * IN_CAPS + ic;
        if (aa == 16) act_s[k] = val;
        else          POSE(k, aa) = val;
    }
    __syncthreads();

    // ---- W fragment: wreg[i][bb] = W[i][o][bb][c] ----
    float wreg[IN_CAPS][4];
    #pragma unroll
    for (int i = 0; i < IN_CAPS; ++i)
        #pragma unroll
        for (int bb = 0; bb < 4; ++bb)
            wreg[i][bb] = w_s[((i * OUT_CAPS + o) * 4 + bb) * 4 + c];

    // ---- votes: vote[k] = sum_b pose[k][a][b] * W[ic][o][b][c] ----
    float vote[KKIN];
    #pragma unroll
    for (int k = 0; k < KKIN; ++k) {
        const float4 pv = *reinterpret_cast<const float4*>(&POSE(k, a * 4));
        const int ic = k & 7;
        vote[k] = pv.x * wreg[ic][0] + pv.y * wreg[ic][1]
                + pv.z * wreg[ic][2] + pv.w * wreg[ic][3];
    }

    // ---- r=0 coupling: softmax(0)*act = act/16 (skip softmax entirely) ----
    if (tid < KKIN) {
        float cv = act_s[tid] * 0.0625f;
        #pragma unroll
        for (int j = 0; j < OUT_CAPS; ++j) coup_t[j][tid] = cv;
    }
    float lreg[5] = {0.f, 0.f, 0.f, 0.f, 0.f};   // logits[16j+e][o] per lane
    __syncthreads();

    // ---- routing-by-agreement ----
    float v = 0.f;
    for (int r = 0; r < 3; ++r) {
        // phase B: s(o,e) = sum_k coup[k][o]*vote[k]  (vector LDS, local k-sum)
        float s = 0.f;
        #pragma unroll
        for (int kc = 0; kc < KKIN / 4; ++kc) {
            const float4 cp = *reinterpret_cast<const float4*>(&coup_t[o][kc * 4]);
            s = fmaf(cp.x, vote[kc * 4 + 0], s);
            s = fmaf(cp.y, vote[kc * 4 + 1], s);
            s = fmaf(cp.z, vote[kc * 4 + 2], s);
            s = fmaf(cp.w, vote[kc * 4 + 3], s);
        }
        // phase C: squash  (||s||^2 over the 16 e-lanes, DPP)
        float sq = row_sum16(s * s);
        v = s * (sq / ((1.f + sq) * sqrtf(sq + 1e-7f)));

        if (r < 2) {
            // phase D: logits[k][o] += sum_e vote*v ; accumulate in lreg
            #pragma unroll
            for (int k = 0; k < KKIN; ++k) {
                float p = row_sum16(vote[k] * v);
                if ((k & 15) == e) lreg[k >> 4] += p;
            }
            // publish logits rows (clobbers pose region - pose is dead)
            #pragma unroll
            for (int j = 0; j < 5; ++j) {
                int k = j * 16 + e;
                if (k < KKIN) LOGIT(k, o) = lreg[j];
            }
            __syncthreads();
            // phase A: coup[k][o] = softmax_o(logits[k]) * act[k]
            if (tid < KKIN) {
                const int k = tid;
                float lg[16];
                float mx = -1e30f;
                #pragma unroll
                for (int j = 0; j < 16; ++j) { lg[j] = LOGIT(k, j); mx = fmaxf(mx, lg[j]); }
                float sum = 0.f;
                #pragma unroll
                for (int j = 0; j < 16; ++j) { lg[j] = __expf(lg[j] - mx); sum += lg[j]; }
                const float scale = act_s[k] / sum;
                #pragma unroll
                for (int j = 0; j < 16; ++j) coup_t[j][k] = lg[j] * scale;
            }
            __syncthreads();
        }
    }

    // ---- out[n][o][e], coalesced ----
    out[n * 256 + tid] = v;
}

extern "C" void kernel_launch(void* const* d_in, const int* in_sizes, int n_in,
                              void* d_out, int out_size, void* d_ws, size_t ws_size,
                              hipStream_t stream) {
    const float* x  = (const float*)d_in[0];   // [2,48,48,136] fp32
    const float* Wt = (const float*)d_in[1];   // [8,16,4,4]    fp32
    float* outp = (float*)d_out;               // [2,46,46,16,16] fp32
    capsule_routing_kernel<<<dim3(NPIX), dim3(256), 0, stream>>>(x, Wt, outp);
}

// Round 3
// 153.583 us; speedup vs baseline: 1.4716x; 1.4533x over previous
//
#include <hip/hip_runtime.h>

// ConvCapsuleLayer: B=2, 48x48, IN_CAPS=8, ATOMS=16, KER=3, OUT_CAPS=16, R=3.
// One 256-thread block per pixel (N=4232). Thread t=(o=t>>4, e=t&15).
// Round-3 design: votes RECOMPUTED from LDS pose at each use (4 FMA, exact)
// -> no vote[72] register array -> low VGPR (target ~80, 6 waves/SIMD) and
// compact rolled loops (r-loop and phase-B p-loop NOT unrolled) to keep the
// code footprint small (~8 KB vs ~18 KB fully-unrolled in round 2).

#define IN_CAPS 8
#define OUT_CAPS 16
#define KK 9
#define KKIN 72          // 9*8
#define BATCH 2
#define H_IN 48
#define W_IN 48
#define HO 46
#define WO 46
#define CIN 136          // 8*17
#define NPIX (BATCH*HO*WO)   // 4232

template<int CTRL>
__device__ __forceinline__ float dpp_f(float x) {
    return __int_as_float(
        __builtin_amdgcn_update_dpp(0, __float_as_int(x), CTRL, 0xF, 0xF, true));
}
// sum across the 16 lanes of a DPP row (our e-group): 4 pure-VALU adds
__device__ __forceinline__ float row_sum16(float x) {
    x += dpp_f<0xB1>(x);    // quad_perm xor1
    x += dpp_f<0x4E>(x);    // quad_perm xor2
    x += dpp_f<0x124>(x);   // row_ror:4
    x += dpp_f<0x128>(x);   // row_ror:8
    return x;
}

__global__ __launch_bounds__(256, 4)
void capsule_routing_kernel(const float* __restrict__ x,
                            const float* __restrict__ Wg,
                            float* __restrict__ out)
{
    __shared__ alignas(16) float pose_s[KKIN * 20];   // [k][atom], stride 20
    __shared__ float act_s[KKIN];
    __shared__ float logits_s[KKIN * 17];             // [k][o], stride 17
    __shared__ float coup_s[OUT_CAPS * 76];           // [o][k], stride 76
    __shared__ float w_s[IN_CAPS * OUT_CAPS * 16];    // 8 KB
    // total ~24 KB -> ~6 blocks/CU if VGPR permits

    const int tid = threadIdx.x;
    const int o = tid >> 4;        // out capsule
    const int e = tid & 15;        // atom = a*4+c
    const int a = e >> 2;
    const int c = e & 3;

    const int n   = blockIdx.x;
    const int b   = n / (HO * WO);
    const int rem = n - b * (HO * WO);
    const int ho  = rem / WO;
    const int wo  = rem - ho * WO;

    // ---- stage W (coalesced) ----
    for (int i = tid; i < IN_CAPS * OUT_CAPS * 16; i += 256) w_s[i] = Wg[i];

    // ---- 3x3 patch: 9 px x 136 ch ----
    for (int idx = tid; idx < KK * CIN; idx += 256) {
        int p  = idx / CIN;
        int cc = idx - p * CIN;
        int py = p / 3, px = p - py * 3;
        float val = x[(((b * H_IN + ho + py) * W_IN) + (wo + px)) * CIN + cc];
        int ic = cc / 17;
        int aa = cc - ic * 17;
        int k  = p * IN_CAPS + ic;
        if (aa == 16) act_s[k] = val;
        else          pose_s[k * 20 + aa] = val;
    }
    __syncthreads();

    // ---- W fragment: wreg[ic][bb] = W[ic][o][bb][c]  (32 VGPRs) ----
    float wreg[IN_CAPS][4];
    #pragma unroll
    for (int i = 0; i < IN_CAPS; ++i)
        #pragma unroll
        for (int bb = 0; bb < 4; ++bb)
            wreg[i][bb] = w_s[((i * OUT_CAPS + o) * 4 + bb) * 4 + c];

    // ---- r=0 coupling: softmax(0)*act = act/16 ----
    if (tid < KKIN) {
        float cv = act_s[tid] * 0.0625f;
        #pragma unroll
        for (int j = 0; j < OUT_CAPS; ++j) coup_s[j * 76 + tid] = cv;
    }
    __syncthreads();

    const float* pose_ae = &pose_s[a * 4];   // this thread's pose row slice
    float lreg[5] = {0.f, 0.f, 0.f, 0.f, 0.f};  // logits[16j+e][o] per lane
    float v = 0.f;

    #pragma unroll 1
    for (int r = 0; r < 3; ++r) {
        // ---- phase B: s(o,e) = sum_k coup[k][o] * vote[k] (vote recomputed) ----
        float s0 = 0.f, s1 = 0.f;
        #pragma unroll 1
        for (int p = 0; p < KK; ++p) {
            const float* pk = pose_ae + p * (8 * 20);
            const float* ck = &coup_s[o * 76 + p * 8];
            #pragma unroll
            for (int ic = 0; ic < 8; ++ic) {
                const float4 pv = *reinterpret_cast<const float4*>(pk + ic * 20);
                float vt = pv.x * wreg[ic][0] + pv.y * wreg[ic][1]
                         + pv.z * wreg[ic][2] + pv.w * wreg[ic][3];
                if (ic & 1) s1 = fmaf(ck[ic], vt, s1);
                else        s0 = fmaf(ck[ic], vt, s0);
            }
        }
        float s = s0 + s1;

        // ---- phase C: squash (||s||^2 over 16 e-lanes via DPP) ----
        float sq = row_sum16(s * s);
        v = s * (sq / ((1.f + sq) * sqrtf(sq + 1e-7f)));

        if (r < 2) {
            // ---- phase D: logits[k][o] += sum_e vote*v (vote recomputed) ----
            #pragma unroll
            for (int k = 0; k < KKIN; ++k) {
                const float4 pv = *reinterpret_cast<const float4*>(pose_ae + k * 20);
                const int ic = k & 7;
                float vt = pv.x * wreg[ic][0] + pv.y * wreg[ic][1]
                         + pv.z * wreg[ic][2] + pv.w * wreg[ic][3];
                float ps = row_sum16(vt * v);
                if ((k & 15) == e) lreg[k >> 4] += ps;   // static k -> cndmask
            }
            // publish logits rows
            #pragma unroll
            for (int j = 0; j < 5; ++j) {
                int k = j * 16 + e;
                if (k < KKIN) logits_s[k * 17 + o] = lreg[j];
            }
            __syncthreads();
            // ---- phase A: coup[k][o] = softmax_o(logits[k]) * act[k] ----
            if (tid < KKIN) {
                const int k = tid;
                float lg[16];
                float mx = -1e30f;
                #pragma unroll
                for (int j = 0; j < 16; ++j) {
                    lg[j] = logits_s[k * 17 + j];
                    mx = fmaxf(mx, lg[j]);
                }
                float sum = 0.f;
                #pragma unroll
                for (int j = 0; j < 16; ++j) { lg[j] = __expf(lg[j] - mx); sum += lg[j]; }
                const float scale = act_s[k] / sum;
                #pragma unroll
                for (int j = 0; j < 16; ++j) coup_s[j * 76 + k] = lg[j] * scale;
            }
            __syncthreads();
        }
    }

    // ---- out[n][o][e], coalesced ----
    out[n * 256 + tid] = v;
}

extern "C" void kernel_launch(void* const* d_in, const int* in_sizes, int n_in,
                              void* d_out, int out_size, void* d_ws, size_t ws_size,
                              hipStream_t stream) {
    const float* x  = (const float*)d_in[0];   // [2,48,48,136] fp32
    const float* Wt = (const float*)d_in[1];   // [8,16,4,4]    fp32
    float* outp = (float*)d_out;               // [2,46,46,16,16] fp32
    capsule_routing_kernel<<<dim3(NPIX), dim3(256), 0, stream>>>(x, Wt, outp);
}

// Round 4
// 100.226 us; speedup vs baseline: 2.2550x; 1.5324x over previous
//
#include <hip/hip_runtime.h>

// ConvCapsuleLayer: B=2, 48x48, IN_CAPS=8, ATOMS=16, KER=3, OUT_CAPS=16, R=3.
// One 256-thread block per pixel (N=4232). Thread t=(o=t>>4, a=(t>>2)&3, c=t&3).
//
// Round-4: algebraic factorization removes all vote recomputation:
//  phase B: s[o,a,c] = sum_ic sum_b W[ic,o,b,c] * M[ic,o,a,b],
//           M[ic,o,a,b] = sum_p coup[8p+ic,o]*pose[8p+ic,a,b]   (lane's c = b role)
//  phase D: P[k,o] = sum_{a,b} pose[k,a,b] * G[ic,o,a,b],
//           G[ic,o,a,b] = sum_c W[ic,o,b,c]*v[o,a,c]  (quad DPP broadcast of v)
//  dots reassigned to (kbase,o) threads: plain 16-FMA dot products, float4 reads.
// Logits accumulate in registers (thread owns its (k,o) pairs across rounds).

#define IN_CAPS 8
#define OUT_CAPS 16
#define KK 9
#define KKIN 72
#define BATCH 2
#define H_IN 48
#define W_IN 48
#define HO 46
#define WO 46
#define CIN 136
#define NPIX (BATCH*HO*WO)   // 4232

template<int CTRL>
__device__ __forceinline__ float dpp_f(float x) {
    return __int_as_float(
        __builtin_amdgcn_update_dpp(0, __float_as_int(x), CTRL, 0xF, 0xF, true));
}
// sum across the 16 lanes of a DPP row (the e-group): 4 pure-VALU adds
__device__ __forceinline__ float row_sum16(float x) {
    x += dpp_f<0xB1>(x);    // quad_perm xor1
    x += dpp_f<0x4E>(x);    // quad_perm xor2
    x += dpp_f<0x124>(x);   // row_ror:4
    x += dpp_f<0x128>(x);   // row_ror:8
    return x;
}

__global__ __launch_bounds__(256, 4)
void capsule_routing_kernel(const float* __restrict__ x,
                            const float* __restrict__ Wg,
                            float* __restrict__ out)
{
    __shared__ alignas(16) float pose_s[KKIN * 20];        // [k][atom]   5760 B
    __shared__ alignas(16) float pose_t[16 * 76];          // [a*4+b][k]  4864 B
    __shared__ float act_s[KKIN];                          //              288 B
    __shared__ alignas(16) float w_s[2048];                //             8192 B
    __shared__ alignas(16) float coup_s[OUT_CAPS * 76];    // [o][k]      4864 B
    __shared__ alignas(16) float logits_s[KKIN * 20];      // [k][o]      5760 B
    __shared__ alignas(16) float g_s[IN_CAPS * OUT_CAPS * 20]; // [ic][o][16] 10240 B
    // total ~39.0 KB -> 4 blocks/CU

    const int tid = threadIdx.x;
    const int o = tid >> 4;        // out capsule
    const int e = tid & 15;        // atom = a*4+c
    const int a = e >> 2;
    const int c = e & 3;

    const int n   = blockIdx.x;
    const int b   = n / (HO * WO);
    const int rem = n - b * (HO * WO);
    const int ho  = rem / WO;
    const int wo  = rem - ho * WO;

    // ---- stage W (coalesced) ----
    for (int i = tid; i < IN_CAPS * OUT_CAPS * 16; i += 256) w_s[i] = Wg[i];

    // ---- 3x3 patch: 9 px x 136 ch; pose stored in BOTH layouts ----
    for (int idx = tid; idx < KK * CIN; idx += 256) {
        int p  = idx / CIN;
        int cc = idx - p * CIN;
        int py = p / 3, px = p - py * 3;
        float val = x[(((b * H_IN + ho + py) * W_IN) + (wo + px)) * CIN + cc];
        int ic = cc / 17;
        int aa = cc - ic * 17;
        int k  = p * IN_CAPS + ic;
        if (aa == 16) {
            act_s[k] = val;
        } else {
            pose_s[k * 20 + aa] = val;
            pose_t[aa * 76 + k] = val;
        }
    }
    __syncthreads();

    // ---- W fragment: wreg[ic][bb] = W[ic][o][bb][c]  (32 VGPRs) ----
    float wreg[IN_CAPS][4];
    #pragma unroll
    for (int i = 0; i < IN_CAPS; ++i)
        #pragma unroll
        for (int bb = 0; bb < 4; ++bb)
            wreg[i][bb] = w_s[((i * OUT_CAPS + o) * 4 + bb) * 4 + c];

    // ---- r=0 coupling: softmax(0)*act = act/16 ----
    if (tid < KKIN) {
        float cv = act_s[tid] * 0.0625f;
        #pragma unroll
        for (int j = 0; j < OUT_CAPS; ++j) coup_s[j * 76 + tid] = cv;
    }
    __syncthreads();

    // phase-D dot assignment: thread (kbase, od) owns k = kbase+16j for j<5
    const int kbase = tid >> 4;          // 0..15
    const int od    = tid & 15;          // phase-D out capsule
    const int icd   = kbase & 7;         // ic of all owned k (16j keeps k&7)
    float lreg[5] = {0.f, 0.f, 0.f, 0.f, 0.f};

    const float4* cp = reinterpret_cast<const float4*>(&coup_s[o * 76]);
    const float4* pp = reinterpret_cast<const float4*>(&pose_t[e * 76]);

    float v = 0.f;
    #pragma unroll 1
    for (int r = 0; r < 3; ++r) {
        // ---- phase B: M[ic] = sum_p coup[8p+ic][o] * pose_t[e][8p+ic] ----
        float M[8] = {0.f,0.f,0.f,0.f,0.f,0.f,0.f,0.f};
        #pragma unroll
        for (int p = 0; p < KK; ++p) {
            const float4 c0 = cp[2*p], c1 = cp[2*p+1];
            const float4 p0 = pp[2*p], p1 = pp[2*p+1];
            M[0] = fmaf(c0.x, p0.x, M[0]);
            M[1] = fmaf(c0.y, p0.y, M[1]);
            M[2] = fmaf(c0.z, p0.z, M[2]);
            M[3] = fmaf(c0.w, p0.w, M[3]);
            M[4] = fmaf(c1.x, p1.x, M[4]);
            M[5] = fmaf(c1.y, p1.y, M[5]);
            M[6] = fmaf(c1.z, p1.z, M[6]);
            M[7] = fmaf(c1.w, p1.w, M[7]);
        }
        // combine: s = sum_ic sum_b wreg[ic][b] * M[ic] (from quad lane b)
        float s0 = 0.f, s1 = 0.f, s2 = 0.f, s3 = 0.f;
        #pragma unroll
        for (int ic = 0; ic < 8; ++ic) {
            s0 = fmaf(wreg[ic][0], dpp_f<0x00>(M[ic]), s0);
            s1 = fmaf(wreg[ic][1], dpp_f<0x55>(M[ic]), s1);
            s2 = fmaf(wreg[ic][2], dpp_f<0xAA>(M[ic]), s2);
            s3 = fmaf(wreg[ic][3], dpp_f<0xFF>(M[ic]), s3);
        }
        const float s = (s0 + s1) + (s2 + s3);

        // ---- phase C: squash ----
        const float sq = row_sum16(s * s);
        v = s * (sq / ((1.f + sq) * sqrtf(sq + 1e-7f)));

        if (r < 2) {
            // ---- phase D part 1: G[ic][o][a][b=c] = sum_c' W[ic][o][c][c']*v[o][a][c'] ----
            const float vq0 = dpp_f<0x00>(v);
            const float vq1 = dpp_f<0x55>(v);
            const float vq2 = dpp_f<0xAA>(v);
            const float vq3 = dpp_f<0xFF>(v);
            #pragma unroll
            for (int ic = 0; ic < 8; ++ic) {
                const float4 wt = *reinterpret_cast<const float4*>(
                    &w_s[((ic * OUT_CAPS + o) * 4 + c) * 4]);
                float g = wt.x * vq0 + wt.y * vq1 + wt.z * vq2 + wt.w * vq3;
                g_s[(ic * OUT_CAPS + o) * 20 + e] = g;
            }
            __syncthreads();
            // ---- phase D part 2: owned dots P[k][od] = sum_{a,b} pose*G ----
            const float4* gp = reinterpret_cast<const float4*>(
                &g_s[(icd * OUT_CAPS + od) * 20]);
            const float4 g0 = gp[0], g1 = gp[1], g2 = gp[2], g3 = gp[3];
            #pragma unroll
            for (int j = 0; j < 5; ++j) {
                const int k = kbase + 16 * j;
                if (k < KKIN) {   // wave-uniform
                    const float4* pk = reinterpret_cast<const float4*>(&pose_s[k * 20]);
                    const float4 p0 = pk[0], p1 = pk[1], p2 = pk[2], p3 = pk[3];
                    float d0 = p0.x*g0.x + p0.y*g0.y + p0.z*g0.z + p0.w*g0.w;
                    float d1 = p1.x*g1.x + p1.y*g1.y + p1.z*g1.z + p1.w*g1.w;
                    float d2 = p2.x*g2.x + p2.y*g2.y + p2.z*g2.z + p2.w*g2.w;
                    float d3 = p3.x*g3.x + p3.y*g3.y + p3.z*g3.z + p3.w*g3.w;
                    lreg[j] += (d0 + d1) + (d2 + d3);
                    logits_s[k * 20 + od] = lreg[j];
                }
            }
            __syncthreads();
            // ---- phase A: coup[k][o] = softmax_o(logits[k]) * act[k] ----
            if (tid < KKIN) {
                const float4* lp = reinterpret_cast<const float4*>(&logits_s[tid * 20]);
                const float4 l0 = lp[0], l1 = lp[1], l2 = lp[2], l3 = lp[3];
                float lg[16] = {l0.x,l0.y,l0.z,l0.w, l1.x,l1.y,l1.z,l1.w,
                                l2.x,l2.y,l2.z,l2.w, l3.x,l3.y,l3.z,l3.w};
                float mx = -1e30f;
                #pragma unroll
                for (int j = 0; j < 16; ++j) mx = fmaxf(mx, lg[j]);
                float sum = 0.f;
                #pragma unroll
                for (int j = 0; j < 16; ++j) { lg[j] = __expf(lg[j] - mx); sum += lg[j]; }
                const float scale = act_s[tid] / sum;
                #pragma unroll
                for (int j = 0; j < 16; ++j) coup_s[j * 76 + tid] = lg[j] * scale;
            }
            __syncthreads();
        }
    }

    // ---- out[n][o][e], coalesced ----
    out[n * 256 + tid] = v;
}

extern "C" void kernel_launch(void* const* d_in, const int* in_sizes, int n_in,
                              void* d_out, int out_size, void* d_ws, size_t ws_size,
                              hipStream_t stream) {
    const float* x  = (const float*)d_in[0];   // [2,48,48,136] fp32
    const float* Wt = (const float*)d_in[1];   // [8,16,4,4]    fp32
    float* outp = (float*)d_out;               // [2,46,46,16,16] fp32
    capsule_routing_kernel<<<dim3(NPIX), dim3(256), 0, stream>>>(x, Wt, outp);
}